// Round 21
// baseline (1043.699 us; speedup 1.0000x reference)
//
#include <hip/hip_runtime.h>
#include <math.h>

#define BATCH 4
#define CIN 64
#define S 48
#define SPAT (48*48*48)
#define HEADS 4
#define HC 24
#define HD 96
#define OCT 8
#define M 8
#define NPTS 13824

// ---------------- Kernel 1: pooled centers + agg init (round-2 exact) --------
__global__ __launch_bounds__(256) void k_centers(
    const float* __restrict__ x, const float* __restrict__ Wf,
    const float* __restrict__ bfp, const float* __restrict__ Wv,
    const float* __restrict__ bvp,
    float* __restrict__ cnorm, float* __restrict__ aggnum,
    float* __restrict__ aggden) {
  int blk = blockIdx.x;
  int b = blk >> 6, q = blk & 63;
  int qw = q >> 4, qh = (q >> 2) & 3, qd = q & 3;
  int t = threadIdx.x;
  int lane = t & 63, wv = t >> 6;

  __shared__ float xpool[CIN];
  __shared__ float fc[HD], vc[HD], rinvs[HEADS];

  const float* xb = x + (size_t)b * CIN * SPAT;
  for (int cin = wv; cin < CIN; cin += 4) {
    const float* xc = xb + (size_t)cin * SPAT;
    float p = 0.f;
    for (int j = lane; j < 1728; j += 64) {
      int lw = j / 144, lh = (j / 12) % 12, ld = j % 12;
      int w = qw * 12 + lw, h = qh * 12 + lh, d = qd * 12 + ld;
      p += xc[(w * S + h) * S + d];
    }
#pragma unroll
    for (int s = 32; s; s >>= 1) p += __shfl_down(p, s, 64);
    if (lane == 0) xpool[cin] = p * (1.f / 1728.f);
  }
  __syncthreads();

  if (t < 192) {
    int k = (t < 96) ? t : t - 96;
    const float* Wrow = ((t < 96) ? Wf : Wv) + k * CIN;
    float acc = (t < 96) ? bfp[k] : bvp[k];
#pragma unroll
    for (int c = 0; c < CIN; c++) acc += Wrow[c] * xpool[c];
    if (t < 96) fc[k] = acc; else vc[k] = acc;
  }
  __syncthreads();

  if (t < HEADS) {
    float ss = 0.f;
#pragma unroll
    for (int c = 0; c < HC; c++) { float v = fc[t * HC + c]; ss += v * v; }
    rinvs[t] = 1.f / fmaxf(sqrtf(ss), 1e-12f);
  }
  __syncthreads();

  int o = ((qw >> 1) << 2) | ((qh >> 1) << 1) | (qd >> 1);
  int m = ((qw & 1) << 2) | ((qh & 1) << 1) | (qd & 1);
  if (t < HD) {
    int e = t / HC, c = t % HC;
    size_t oidx = ((((size_t)b * HEADS + e) * OCT + o) * M + m) * HC + c;
    cnorm[oidx] = fc[t] * rinvs[e];
    aggnum[oidx] = vc[t];
  }
  if (t < HEADS) {
    aggden[(((size_t)b * HEADS + t) * OCT + o) * M + m] = 1.0f;
  }
}

// ---------------- Kernel 2: streaming-GEMV conv + sim + argmax + aggregate ----
// Round-2 arithmetic EXACTLY (same per-accumulator summation order, same
// __expf, same strict-> argmax) but restructured for occupancy: no xr[64]
// array (16-ch register chunks, 16 coalesced loads in flight), f+v fused in
// one x pass per head (~80 VGPR vs round-2's 136 @ 10.5% occupancy).
__global__ __launch_bounds__(256) void k_assign(
    const float* __restrict__ x, const float* __restrict__ Wf,
    const float* __restrict__ bf_, const float* __restrict__ Wv,
    const float* __restrict__ bv_, const float* __restrict__ cnorm,
    const float* __restrict__ salpha, const float* __restrict__ sbeta,
    float* __restrict__ aggnum, float* __restrict__ aggden,
    float* __restrict__ simbuf, unsigned char* __restrict__ idxbuf) {
  int blk = blockIdx.x;
  int chunk = blk % 54;
  int bo = blk / 54;
  int o = bo & 7, b = bo >> 3;
  int t = threadIdx.x;
  int n = chunk * 256 + t;
  int wp = n / 576, hp = (n / 24) % 24, dp = n % 24;
  int ow = (o >> 2) & 1, oh = (o >> 1) & 1, od = o & 1;
  int w = ow * 24 + wp, h = oh * 24 + hp, d = od * 24 + dp;

  __shared__ float lagg[HEADS][M][HC + 1];
  for (int i = t; i < HEADS * M * (HC + 1); i += 256) ((float*)lagg)[i] = 0.f;
  __syncthreads();

  const float* xb = x + (size_t)b * CIN * SPAT + (size_t)(w * S + h) * S + d;
  float alpha = salpha[0], beta = sbeta[0];

#pragma unroll 1
  for (int e = 0; e < HEADS; e++) {
    float f[HC], v[HC];
#pragma unroll
    for (int c = 0; c < HC; c++) { f[c] = bf_[e * HC + c]; v[c] = bv_[e * HC + c]; }

    // stream x in 4 chunks of 16 channels; weights via uniform scalar loads.
    // Per-accumulator add order = ascending ci  ==  round-2 arithmetic.
#pragma unroll 1
    for (int cb = 0; cb < 4; cb++) {
      float xr[16];
#pragma unroll
      for (int j = 0; j < 16; j++) xr[j] = xb[(size_t)(cb * 16 + j) * SPAT];
#pragma unroll
      for (int j = 0; j < 16; j++) {
        float xv = xr[j];
        const float* wf = Wf + (e * HC) * CIN + cb * 16 + j;
        const float* wvp = Wv + (e * HC) * CIN + cb * 16 + j;
#pragma unroll
        for (int c = 0; c < HC; c++) {
          f[c] += wf[c * CIN] * xv;
          v[c] += wvp[c * CIN] * xv;
        }
      }
    }

    float ss = 0.f;
#pragma unroll
    for (int c = 0; c < HC; c++) ss += f[c] * f[c];
    float rinv = 1.f / fmaxf(sqrtf(ss), 1e-12f);

    const float* cn = cnorm + (((size_t)b * HEADS + e) * OCT + o) * M * HC;
    float best = -1.f;
    int bm = 0;
#pragma unroll
    for (int m = 0; m < M; m++) {
      float dt = 0.f;
#pragma unroll
      for (int c = 0; c < HC; c++) dt += cn[m * HC + c] * f[c];
      float cosv = dt * rinv;
      float sim = 1.f / (1.f + __expf(-(beta + alpha * cosv)));
      if (sim > best) { best = sim; bm = m; }
    }

    size_t pidx = (((size_t)b * HEADS + e) * OCT + o) * (size_t)NPTS + n;
    simbuf[pidx] = best;
    idxbuf[pidx] = (unsigned char)bm;

#pragma unroll
    for (int c = 0; c < HC; c++) atomicAdd(&lagg[e][bm][c], best * v[c]);
    atomicAdd(&lagg[e][bm][HC], best);
  }
  __syncthreads();

  for (int i = t; i < HEADS * M * (HC + 1); i += 256) {
    int e = i / (M * (HC + 1));
    int r = i % (M * (HC + 1));
    int m = r / (HC + 1), c = r % (HC + 1);
    float val = lagg[e][m][c];
    size_t base = (((size_t)b * HEADS + e) * OCT + o) * M + m;
    if (c < HC) atomicAdd(&aggnum[base * HC + c], val);
    else        atomicAdd(&aggden[base], val);
  }
}

// ---------------- Kernel 3: dispatch + unfold + output projection (round-2) ----
__global__ __launch_bounds__(256) void k_out(
    const float* __restrict__ Wp, const float* __restrict__ bp,
    const float* __restrict__ aggnum, const float* __restrict__ aggden,
    const float* __restrict__ simbuf, const unsigned char* __restrict__ idxbuf,
    float* __restrict__ out) {
  int blk = blockIdx.x;
  int b = blk / 432;
  int p = (blk % 432) * 256 + threadIdx.x;
  int w = p / 2304, h = (p / 48) % 48, d = p % 48;
  int ow = w / 24, oh = h / 24, od = d / 24;
  int o = ow * 4 + oh * 2 + od;
  int wp = w % 24, hp = h % 24, dp = d % 24;
  int n = (wp * 24 + hp) * 24 + dp;

  float pre[HD];
#pragma unroll
  for (int e = 0; e < HEADS; e++) {
    size_t pidx = (((size_t)b * HEADS + e) * OCT + o) * (size_t)NPTS + n;
    float s = simbuf[pidx];
    int m = idxbuf[pidx];
    size_t aidx = (((size_t)b * HEADS + e) * OCT + o) * M + m;
    float den = aggden[aidx];
    float sc = s / den;
    const float* nm = aggnum + aidx * HC;
#pragma unroll
    for (int c = 0; c < HC; c++) pre[e * HC + c] = nm[c] * sc;
  }

  float* ob = out + (size_t)b * CIN * SPAT + p;
  for (int co = 0; co < CIN; co++) {
    float acc = bp[co];
#pragma unroll
    for (int k = 0; k < HD; k++) acc += Wp[co * HD + k] * pre[k];
    ob[(size_t)co * SPAT] = acc;
  }
}

extern "C" void kernel_launch(void* const* d_in, const int* in_sizes, int n_in,
                              void* d_out, int out_size, void* d_ws, size_t ws_size,
                              hipStream_t stream) {
  const float* x  = (const float*)d_in[0];
  const float* Wf = (const float*)d_in[1];
  const float* bf_ = (const float*)d_in[2];
  const float* Wv = (const float*)d_in[3];
  const float* bv_ = (const float*)d_in[4];
  const float* Wp = (const float*)d_in[5];
  const float* bp = (const float*)d_in[6];
  const float* sa = (const float*)d_in[7];
  const float* sb = (const float*)d_in[8];
  float* out = (float*)d_out;

  // Round-2 proven layout (9.05 MB).
  float* ws = (float*)d_ws;
  float* cnorm  = ws;                    // 24576 f
  float* aggnum = cnorm + 24576;         // 24576 f
  float* aggden = aggnum + 24576;        // 1024 f
  float* simbuf = aggden + 1024;         // 1769472 f
  unsigned char* idxbuf = (unsigned char*)(simbuf + 1769472);  // 1769472 bytes

  k_centers<<<BATCH * 64, 256, 0, stream>>>(x, Wf, bf_, Wv, bv_, cnorm, aggnum, aggden);
  k_assign<<<BATCH * OCT * 54, 256, 0, stream>>>(x, Wf, bf_, Wv, bv_, cnorm, sa, sb,
                                                 aggnum, aggden, simbuf, idxbuf);
  k_out<<<BATCH * 432, 256, 0, stream>>>(Wp, bp, aggnum, aggden, simbuf, idxbuf, out);
}